// Round 8
// baseline (216.737 us; speedup 1.0000x reference)
//
#include <hip/hip_runtime.h>
#include <hip/hip_cooperative_groups.h>

namespace cg = cooperative_groups;

// STDP Linear layer: B=64, IN=4096, OUT=1024, all fp32.
// Outputs concatenated in d_out: spikes[64,1024] | mem[64,1024] |
// w_new[1024,4096] | tp[64,4096] | tq[64,1024]
//
// ONE cooperative kernel, 512 blocks x 256 threads, two grid.sync()s:
//   phase 1: gemm1 splitK on MFMA (bf16 hi/lo split, hh+hl+lh)
//   phase 2: reduce partials + LIF + tq + tp
//   phase 3: w_new rank-64 update (each block: 2 o-tiles, shared i-slice)

#define B_    64
#define IN_   4096
#define OUT_  1024
#define SPLITS 32
#define KC    128   // k-range per block
#define BK    64    // k-chunk staged in LDS

static constexpr int OFF_SPIKES = 0;
static constexpr int OFF_MEM    = B_ * OUT_;               // 65536
static constexpr int OFF_W      = 2 * B_ * OUT_;           // 131072
static constexpr int OFF_TP     = OFF_W + OUT_ * IN_;      // 4325376
static constexpr int OFF_TQ     = OFF_TP + B_ * IN_;       // 4587520

typedef short          s16x8 __attribute__((ext_vector_type(8)));
typedef unsigned short u16x8 __attribute__((ext_vector_type(8)));
typedef float          f32x4 __attribute__((ext_vector_type(4)));

__device__ __forceinline__ unsigned short bf16_rne(float x) {
  unsigned u = __float_as_uint(x);
  return (unsigned short)((u + 0x7fffu + ((u >> 16) & 1u)) >> 16);
}

// LDS: phase 1 needs 4x[64][64] u16 (32 KB); phase 3 needs 2x[64][68] f32
// (34.8 KB). Union them; 34.8 KB/block -> up to 4 blocks/CU, we run 2.
struct SharedU {
  union {
    struct { unsigned short Ah[64][64], Al[64][64], Wh[64][64], Wl[64][64]; } g;
    struct { float tpl[64][68], tql[64][68]; } w;
  };
};

__global__ __launch_bounds__(256) void k_fused(const float* __restrict__ A,
                                               const float* __restrict__ Wt,
                                               const float* __restrict__ membrane,
                                               const float* __restrict__ trace_pre,
                                               const float* __restrict__ trace_post,
                                               float* __restrict__ out,
                                               float* __restrict__ part) {
  cg::grid_group grid = cg::this_grid();
  __shared__ SharedU sh;

  const int bid  = blockIdx.x;   // 0..511
  const int t    = threadIdx.x;
  const int lane = t & 63;
  const int w    = t >> 6;

  // ========================= phase 1: gemm partials ========================
  // block = (nb = bid&15, ks = bid>>4): 64b x 64n x 128k, two BK=64 chunks.
  // 16B-chunk XOR swizzle: chunk j of row r at j ^ (r&7) (2-way = free).
  {
    const int nb = bid & 15;
    const int ks = bid >> 4;

    f32x4 acc[4];
#pragma unroll
    for (int bt = 0; bt < 4; ++bt) acc[bt] = (f32x4){0.f, 0.f, 0.f, 0.f};

#pragma unroll
    for (int c = 0; c < 2; ++c) {
      const int k0 = ks * KC + c * BK;
      if (c) __syncthreads();          // previous chunk's MFMA reads done

      // ---- stage: fp32 -> bf16 hi/lo, swizzled 16B chunks ----
#pragma unroll
      for (int s = t; s < 512; s += 256) {
        const int r  = s >> 3;
        const int j  = s & 7;
        const int jc = (j ^ (r & 7)) << 3;     // dest column (u16 units)

        const float* ap = A + (size_t)r * IN_ + k0 + j * 8;
        const float4 a0 = *reinterpret_cast<const float4*>(ap);
        const float4 a1 = *reinterpret_cast<const float4*>(ap + 4);
        const float  af[8] = {a0.x, a0.y, a0.z, a0.w, a1.x, a1.y, a1.z, a1.w};
        u16x8 ahi, alo;
#pragma unroll
        for (int e = 0; e < 8; ++e) {
          const unsigned short h = bf16_rne(af[e]);
          ahi[e] = h;
          alo[e] = bf16_rne(af[e] - __uint_as_float(((unsigned)h) << 16));
        }
        *reinterpret_cast<u16x8*>(&sh.g.Ah[r][jc]) = ahi;
        *reinterpret_cast<u16x8*>(&sh.g.Al[r][jc]) = alo;

        const float* wp = Wt + (size_t)(nb * 64 + r) * IN_ + k0 + j * 8;
        const float4 w0 = *reinterpret_cast<const float4*>(wp);
        const float4 w1 = *reinterpret_cast<const float4*>(wp + 4);
        const float  wf[8] = {w0.x, w0.y, w0.z, w0.w, w1.x, w1.y, w1.z, w1.w};
        u16x8 whi, wlo;
#pragma unroll
        for (int e = 0; e < 8; ++e) {
          const unsigned short h = bf16_rne(wf[e]);
          whi[e] = h;
          wlo[e] = bf16_rne(wf[e] - __uint_as_float(((unsigned)h) << 16));
        }
        *reinterpret_cast<u16x8*>(&sh.g.Wh[r][jc]) = whi;
        *reinterpret_cast<u16x8*>(&sh.g.Wl[r][jc]) = wlo;
      }
      __syncthreads();

      // ---- MFMA: two k-steps of 32 per chunk; wave w owns n-strip w*16 ----
#pragma unroll
      for (int kk = 0; kk < 2; ++kk) {
        const int c4 = kk * 4 + (lane >> 4);       // 16B-chunk index 0..7
        const int jc = (c4 ^ (lane & 7)) << 3;     // swizzled column
        const int nloc = w * 16 + (lane & 15);

        const s16x8 whi = *reinterpret_cast<const s16x8*>(&sh.g.Wh[nloc][jc]);
        const s16x8 wlo = *reinterpret_cast<const s16x8*>(&sh.g.Wl[nloc][jc]);
#pragma unroll
        for (int bt = 0; bt < 4; ++bt) {
          const int bloc = bt * 16 + (lane & 15);
          const s16x8 ahi = *reinterpret_cast<const s16x8*>(&sh.g.Ah[bloc][jc]);
          const s16x8 alo = *reinterpret_cast<const s16x8*>(&sh.g.Al[bloc][jc]);
          acc[bt] = __builtin_amdgcn_mfma_f32_16x16x32_bf16(ahi, whi, acc[bt], 0, 0, 0);
          acc[bt] = __builtin_amdgcn_mfma_f32_16x16x32_bf16(ahi, wlo, acc[bt], 0, 0, 0);
          acc[bt] = __builtin_amdgcn_mfma_f32_16x16x32_bf16(alo, whi, acc[bt], 0, 0, 0);
        }
      }
    }

    // ---- write partials: part[ks][b][n]; C/D map col=lane&15, row=(lane>>4)*4+reg
    const int n_g = nb * 64 + w * 16 + (lane & 15);
#pragma unroll
    for (int bt = 0; bt < 4; ++bt) {
#pragma unroll
      for (int reg = 0; reg < 4; ++reg) {
        const int b = bt * 16 + (lane >> 4) * 4 + reg;
        part[((size_t)(ks * 64 + b)) * OUT_ + n_g] = acc[bt][reg];
      }
    }
  }

  grid.sync();   // partials visible device-wide

  // ================= phase 2: reduce + LIF + tq + tp =======================
  {
    const int g = bid * 256 + t;       // 0..131071
    if (g < B_ * OUT_) {
      const int b = g >> 10;
      const int n = g & (OUT_ - 1);

      float s0 = 0.f, s1 = 0.f, s2 = 0.f, s3 = 0.f;
#pragma unroll
      for (int ks = 0; ks < SPLITS; ks += 4) {
        s0 += part[((size_t)((ks + 0) * B_ + b)) * OUT_ + n];
        s1 += part[((size_t)((ks + 1) * B_ + b)) * OUT_ + n];
        s2 += part[((size_t)((ks + 2) * B_ + b)) * OUT_ + n];
        s3 += part[((size_t)((ks + 3) * B_ + b)) * OUT_ + n];
      }
      const float weighted = (s0 + s1) + (s2 + s3);

      const float mem   = fmaf(membrane[g], 0.98f, weighted);
      const float spike = (mem > 0.4f) ? 1.0f : 0.0f;
      const float memo  = (spike > 0.0f) ? 0.0f : mem;
      float tq = fmaf(trace_post[n], 0.85f, spike);
      tq = fminf(fmaxf(tq, 0.0f), 1.0f);

      out[OFF_SPIKES + g] = spike;
      out[OFF_MEM    + g] = memo;
      out[OFF_TQ     + g] = tq;

      // tp: one float4 per thread (65536 float4 total)
      const int i4 = g & (IN_ / 4 - 1);
      const float4 x  = reinterpret_cast<const float4*>(A)[g];
      const float4 tr = reinterpret_cast<const float4*>(trace_pre)[i4];
      float4 r;
      r.x = fminf(fmaxf(fmaf(tr.x, 0.85f, x.x), 0.0f), 1.0f);
      r.y = fminf(fmaxf(fmaf(tr.y, 0.85f, x.y), 0.0f), 1.0f);
      r.z = fminf(fmaxf(fmaf(tr.z, 0.85f, x.z), 0.0f), 1.0f);
      r.w = fminf(fmaxf(fmaf(tr.w, 0.85f, x.w), 0.0f), 1.0f);
      reinterpret_cast<float4*>(out + OFF_TP)[g] = r;
    }
  }

  grid.sync();   // tp/tq visible; partials consumed (phase 3 overwrites them)

  // ==================== phase 3: w_new rank-64 update ======================
  // block bid handles tiles (i = bid&63, o = bid>>6) and (same i, o + 8);
  // tpl (i-slice) staged once, tql reloaded per o-tile.
  {
    const float* tp = out + OFF_TP;
    const float* tq = out + OFF_TQ;
    float* wout = out + OFF_W;

    const int i0 = (bid & 63) * 64;
    const int c4 = t & 15;
    const int rr = t >> 4;       // 0..15: load rows rr, rr+16, rr+32, rr+48
#pragma unroll
    for (int r = 0; r < 4; ++r) {
      const int b = rr + r * 16;
      *reinterpret_cast<float4*>(&sh.w.tpl[b][c4 * 4]) =
          *reinterpret_cast<const float4*>(tp + (size_t)b * IN_ + i0 + c4 * 4);
    }

    const int il = t & 15;
    const int ol = t >> 4;

#pragma unroll
    for (int half = 0; half < 2; ++half) {
      const int o0 = ((bid >> 6) + half * 8) * 64;
      if (half) __syncthreads();       // drain previous compute before tql reuse
#pragma unroll
      for (int r = 0; r < 4; ++r) {
        const int b = rr + r * 16;
        *reinterpret_cast<float4*>(&sh.w.tql[b][c4 * 4]) =
            *reinterpret_cast<const float4*>(tq + (size_t)b * OUT_ + o0 + c4 * 4);
      }
      __syncthreads();

      float acc[4][4];
#pragma unroll
      for (int u = 0; u < 4; ++u)
#pragma unroll
        for (int v = 0; v < 4; ++v) acc[u][v] = 0.f;

#pragma unroll 4
      for (int b = 0; b < 64; ++b) {
        const float4 tpv = *reinterpret_cast<const float4*>(&sh.w.tpl[b][il * 4]);
        const float4 tqv = *reinterpret_cast<const float4*>(&sh.w.tql[b][ol * 4]);
        const float tp4[4] = {tpv.x, tpv.y, tpv.z, tpv.w};
        const float tq4[4] = {tqv.x, tqv.y, tqv.z, tqv.w};
#pragma unroll
        for (int u = 0; u < 4; ++u)
#pragma unroll
          for (int v = 0; v < 4; ++v)
            acc[u][v] = fmaf(tq4[u], tp4[v], acc[u][v]);
      }

      const float cdw = (float)(0.005 - 0.004);   // A_POS - A_NEG
#pragma unroll
      for (int u = 0; u < 4; ++u) {
        const int o = o0 + ol * 4 + u;
        const float4 wv = *reinterpret_cast<const float4*>(
            Wt + (size_t)o * IN_ + i0 + il * 4);
        float4 r;
        r.x = fminf(fmaxf(fmaf(cdw, acc[u][0], wv.x), -0.1f), 0.5f);
        r.y = fminf(fmaxf(fmaf(cdw, acc[u][1], wv.y), -0.1f), 0.5f);
        r.z = fminf(fmaxf(fmaf(cdw, acc[u][2], wv.z), -0.1f), 0.5f);
        r.w = fminf(fmaxf(fmaf(cdw, acc[u][3], wv.w), -0.1f), 0.5f);
        *reinterpret_cast<float4*>(wout + (size_t)o * IN_ + i0 + il * 4) = r;
      }
    }
  }
}

// ---------------------------------------------------------------------------
extern "C" void kernel_launch(void* const* d_in, const int* in_sizes, int n_in,
                              void* d_out, int out_size, void* d_ws, size_t ws_size,
                              hipStream_t stream) {
  const float* in_spikes  = (const float*)d_in[0];
  const float* weight     = (const float*)d_in[1];
  const float* membrane   = (const float*)d_in[2];
  const float* trace_pre  = (const float*)d_in[3];
  const float* trace_post = (const float*)d_in[4];
  float* out = (float*)d_out;

  // Split-K partials (32 x 64 x 1024 x 4B = 8.4 MB) live in the w_new output
  // region (16.8 MB); consumed in phase 2 before phase 3 overwrites them.
  float* part = out + OFF_W;

  void* args[] = {(void*)&in_spikes, (void*)&weight, (void*)&membrane,
                  (void*)&trace_pre, (void*)&trace_post, (void*)&out,
                  (void*)&part};
  hipLaunchCooperativeKernel((const void*)k_fused, dim3(512), dim3(256),
                             args, 0, stream);
}